// Round 6
// baseline (380.988 us; speedup 1.0000x reference)
//
#include <hip/hip_runtime.h>

// GIN: 2x GINConv(eps=0, MLP 2-layer) + ReLU, then Linear(128->1).
// N=50000 nodes, E=800000 edges, IN=64, HID=128.
//
// Round 6: split-bf16 becomes the STORAGE format for all intermediate
// tensors: packed row = [hi bf16 x K | lo bf16 x K] (same bytes as fp32).
// Gather reconstructs fp32 (hi+lo), accumulates fp32, writes split.
// GEMM staging is now pure copy (no per-k-step split VALU, which was ~2x
// the MFMA time in round 5). out = Ah*Wh + Al*Wh + Ah*Wl (3 MFMA passes).

#define N_NODES 50000
#define IN_CH 64
#define HID 128

typedef short short8 __attribute__((ext_vector_type(8)));
typedef float f32x4 __attribute__((ext_vector_type(4)));

__device__ __forceinline__ unsigned bf16_rne(float f) {
    unsigned u = __float_as_uint(f);
    return (u + 0x7FFFu + ((u >> 16) & 1u)) >> 16;
}

// ---------------- edge dtype detection (int64 vs int32) ----------------
__global__ void detect64_kernel(const int* __restrict__ ei32, int* __restrict__ flag) {
    int t = threadIdx.x;  // 256 threads
    int v = ei32[2 * t + 1];
    unsigned long long b = __ballot(v != 0);
    __shared__ unsigned long long r[4];
    if ((t & 63) == 0) r[t >> 6] = b;
    __syncthreads();
    if (t == 0) flag[0] = ((r[0] | r[1] | r[2] | r[3]) == 0ULL) ? 1 : 0;
}

__device__ __forceinline__ int load_idx(const void* ei, int is64, int pos) {
    if (is64) return (int)((const long long*)ei)[pos];
    return ((const int*)ei)[pos];
}

// ---------------- CSR build ----------------
__global__ __launch_bounds__(256) void hist_kernel(
    const void* __restrict__ ei, const int* __restrict__ is64,
    int* __restrict__ deg, int E)
{
    int e = blockIdx.x * blockDim.x + threadIdx.x;
    if (e >= E) return;
    int d = load_idx(ei, *is64, E + e);
    atomicAdd(&deg[d], 1);
}

__device__ __forceinline__ int wave_incl_scan(int v, int lane) {
    #pragma unroll
    for (int off = 1; off < 64; off <<= 1) {
        int u = __shfl_up(v, off);
        if (lane >= off) v += u;
    }
    return v;
}

__global__ __launch_bounds__(256) void scan1_kernel(
    const int* __restrict__ deg, int* __restrict__ incl,
    int* __restrict__ bsum, int N)
{
    int i = blockIdx.x * 256 + threadIdx.x;
    int lane = threadIdx.x & 63;
    int w = threadIdx.x >> 6;
    int v = (i < N) ? deg[i] : 0;
    int s = wave_incl_scan(v, lane);
    __shared__ int wsum[4];
    if (lane == 63) wsum[w] = s;
    __syncthreads();
    int off = 0;
    #pragma unroll
    for (int k = 0; k < 4; k++) if (k < w) off += wsum[k];
    s += off;
    if (i < N) incl[i] = s;
    if (threadIdx.x == 255) bsum[blockIdx.x] = s;
}

__global__ __launch_bounds__(256) void scan2_kernel(
    const int* __restrict__ bsum, int* __restrict__ bsx, int nb)
{
    int t = threadIdx.x;
    int lane = t & 63;
    int w = t >> 6;
    int v = (t < nb) ? bsum[t] : 0;
    int s = wave_incl_scan(v, lane);
    __shared__ int wsum[4];
    if (lane == 63) wsum[w] = s;
    __syncthreads();
    int off = 0;
    #pragma unroll
    for (int k = 0; k < 4; k++) if (k < w) off += wsum[k];
    s += off;
    if (t < nb) bsx[t] = s - v;   // exclusive
}

__global__ __launch_bounds__(256) void scan3_kernel(
    int* __restrict__ deg_cursor, int* __restrict__ incl_rowptr,
    const int* __restrict__ bsx, int N)
{
    int i = blockIdx.x * 256 + threadIdx.x;
    if (i >= N) return;
    int incl = incl_rowptr[i] + bsx[blockIdx.x];
    int d = deg_cursor[i];
    int excl = incl - d;
    incl_rowptr[i] = excl;        // row_ptr[i]
    deg_cursor[i] = excl;         // cursor[i]
    if (i == N - 1) incl_rowptr[N] = incl;
}

__global__ __launch_bounds__(256) void fill_kernel(
    const void* __restrict__ ei, const int* __restrict__ is64,
    int* __restrict__ cursor, int* __restrict__ col, int E)
{
    int e = blockIdx.x * blockDim.x + threadIdx.x;
    if (e >= E) return;
    int i64 = *is64;
    int s = load_idx(ei, i64, e);
    int d = load_idx(ei, i64, E + e);
    int pos = atomicAdd(&cursor[d], 1);
    col[pos] = s;
}

// ---------------- W split: W fp32 [K][128] -> Wh/Wl bf16 [128][K] (transposed) ----------------
template<int K>
__global__ __launch_bounds__(256) void wsplit_kernel(
    const float* __restrict__ W, ushort* __restrict__ Wh, ushort* __restrict__ Wl)
{
    int i = blockIdx.x * 256 + threadIdx.x;
    if (i >= 128 * K) return;
    int n = i / K, k = i % K;
    float w = W[(size_t)k * 128 + n];
    unsigned h = bf16_rne(w);
    float hf = __uint_as_float(h << 16);
    unsigned lo = bf16_rne(w - hf);
    Wh[(size_t)n * K + k] = (ushort)h;
    Wl[(size_t)n * K + k] = (ushort)lo;
}

// reconstruct fp32 pair from packed-hi uint and packed-lo uint
__device__ __forceinline__ float2 unsplit2(unsigned hi, unsigned lo) {
    float a = __uint_as_float(hi << 16)          + __uint_as_float(lo << 16);
    float b = __uint_as_float(hi & 0xFFFF0000u)  + __uint_as_float(lo & 0xFFFF0000u);
    return make_float2(a, b);
}

// ---------------- gather64: out P64 = split( x[n] + sum_j x[j] ), x fp32 [N][64] ----------------
__global__ __launch_bounds__(256) void gather_agg64_kernel(
    const float* __restrict__ x, const int* __restrict__ rp,
    const int* __restrict__ col, ushort* __restrict__ out, int N)
{
    int wid = (blockIdx.x * blockDim.x + threadIdx.x) >> 6;
    int lane = threadIdx.x & 63;
    if (wid >= N) return;
    int b = rp[wid], e2 = rp[wid + 1];
    float acc = x[(size_t)wid * 64 + lane];   // self term
    for (int base = b; base < e2; base += 64) {
        int cnt = e2 - base; if (cnt > 64) cnt = 64;
        int myc = (base + lane < e2) ? col[base + lane] : 0;
        for (int j = 0; j < cnt; j++) {
            int s = __shfl(myc, j);
            acc += x[(size_t)s * 64 + lane];
        }
    }
    unsigned h = bf16_rne(acc);
    unsigned l = bf16_rne(acc - __uint_as_float(h << 16));
    out[(size_t)wid * 128 + lane]      = (ushort)h;
    out[(size_t)wid * 128 + 64 + lane] = (ushort)l;
}

// ---------------- gather128: in/out P128 (row = 128 uints: 64 hi-pairs | 64 lo-pairs) ----------------
__global__ __launch_bounds__(256) void gather_agg128_kernel(
    const ushort* __restrict__ in, const int* __restrict__ rp,
    const int* __restrict__ col, ushort* __restrict__ out, int N)
{
    const unsigned* inu = (const unsigned*)in;
    unsigned* outu = (unsigned*)out;
    int wid = (blockIdx.x * blockDim.x + threadIdx.x) >> 6;
    int lane = threadIdx.x & 63;
    if (wid >= N) return;
    int b = rp[wid], e2 = rp[wid + 1];
    // self term
    float2 acc;
    {
        unsigned hi = inu[(size_t)wid * 128 + lane];
        unsigned lo = inu[(size_t)wid * 128 + 64 + lane];
        acc = unsplit2(hi, lo);
    }
    for (int base = b; base < e2; base += 64) {
        int cnt = e2 - base; if (cnt > 64) cnt = 64;
        int myc = (base + lane < e2) ? col[base + lane] : 0;
        for (int j = 0; j < cnt; j++) {
            int s = __shfl(myc, j);
            unsigned hi = inu[(size_t)s * 128 + lane];
            unsigned lo = inu[(size_t)s * 128 + 64 + lane];
            float2 v = unsplit2(hi, lo);
            acc.x += v.x; acc.y += v.y;
        }
    }
    unsigned h0 = bf16_rne(acc.x);
    unsigned l0 = bf16_rne(acc.x - __uint_as_float(h0 << 16));
    unsigned h1 = bf16_rne(acc.y);
    unsigned l1 = bf16_rne(acc.y - __uint_as_float(h1 << 16));
    outu[(size_t)wid * 128 + lane]      = h0 | (h1 << 16);
    outu[(size_t)wid * 128 + 64 + lane] = l0 | (l1 << 16);
}

// ---------------- MFMA GEMM: out P128 = relu(A @ W + b); A = P(K) packed split ----------------
// Block: 64 rows x 128 cols, 256 threads (4 waves, 16 rows each).
template<int K>
__global__ __launch_bounds__(256) void gemm_mfma_kernel(
    const ushort* __restrict__ A, const ushort* __restrict__ Whg,
    const ushort* __restrict__ Wlg, const float* __restrict__ bias,
    ushort* __restrict__ out, int N)
{
    __shared__ ushort Ah[64][40], Al[64][40];      // pad to 40 (2-way bank at worst)
    __shared__ ushort Wh[128][40], Wl[128][40];

    const int t  = threadIdx.x;
    const int n0 = blockIdx.x * 64;
    const int w  = t >> 6, l = t & 63;
    const int lr = l & 15, lg = l >> 4;

    f32x4 acc[8];
    #pragma unroll
    for (int c = 0; c < 8; c++) acc[c] = (f32x4){0.f, 0.f, 0.f, 0.f};

    #pragma unroll 1
    for (int k0 = 0; k0 < K; k0 += 32) {
        // ---- stage A tile 64x32 (hi+lo), pure copy: 4 threads/row, 16B each ----
        {
            int row = t >> 2, seg = t & 3;
            int n = n0 + row; int nc = n < N ? n : N - 1;
            const ushort* p = A + (size_t)nc * (2 * K) + k0 + seg * 8;
            uint4 hv = *(const uint4*)p;
            uint4 lv = *(const uint4*)(p + K);
            *(uint4*)&Ah[row][seg * 8] = hv;
            *(uint4*)&Al[row][seg * 8] = lv;
        }
        // ---- stage W tiles 128x32 (hi and lo) ----
        {
            int n = t >> 1, half = t & 1;
            const uint4* ph = (const uint4*)(Whg + (size_t)n * K + k0 + half * 16);
            const uint4* pl = (const uint4*)(Wlg + (size_t)n * K + k0 + half * 16);
            uint4 a0 = ph[0], a1 = ph[1];
            uint4 b0 = pl[0], b1 = pl[1];
            uint4* dh = (uint4*)&Wh[n][half * 16];
            uint4* dl = (uint4*)&Wl[n][half * 16];
            dh[0] = a0; dh[1] = a1;
            dl[0] = b0; dl[1] = b1;
        }
        __syncthreads();
        short8 ah = *(const short8*)&Ah[w * 16 + lr][lg * 8];
        short8 al = *(const short8*)&Al[w * 16 + lr][lg * 8];
        #pragma unroll
        for (int c = 0; c < 8; c++) {
            short8 bh = *(const short8*)&Wh[c * 16 + lr][lg * 8];
            short8 bl = *(const short8*)&Wl[c * 16 + lr][lg * 8];
            acc[c] = __builtin_amdgcn_mfma_f32_16x16x32_bf16(ah, bh, acc[c], 0, 0, 0);
            acc[c] = __builtin_amdgcn_mfma_f32_16x16x32_bf16(al, bh, acc[c], 0, 0, 0);
            acc[c] = __builtin_amdgcn_mfma_f32_16x16x32_bf16(ah, bl, acc[c], 0, 0, 0);
        }
        __syncthreads();
    }
    // ---- epilogue: D col = c*16+lr, row = w*16 + lg*4 + j; write split P128 ----
    #pragma unroll
    for (int c = 0; c < 8; c++) {
        float bc = bias[c * 16 + lr];
        #pragma unroll
        for (int j = 0; j < 4; j++) {
            int row = n0 + w * 16 + lg * 4 + j;
            if (row < N) {
                float v = fmaxf(acc[c][j] + bc, 0.f);
                unsigned h = bf16_rne(v);
                unsigned lo = bf16_rne(v - __uint_as_float(h << 16));
                out[(size_t)row * 256 + c * 16 + lr]       = (ushort)h;
                out[(size_t)row * 256 + 128 + c * 16 + lr] = (ushort)lo;
            }
        }
    }
}

// ---------------- output head: out[n] = dot(h2[n], Wout) + bout; h2 = P128 ----------------
__global__ __launch_bounds__(256) void out_dot_kernel(
    const ushort* __restrict__ h2, const float* __restrict__ Wout,
    const float* __restrict__ bout, float* __restrict__ out, int N)
{
    const unsigned* h2u = (const unsigned*)h2;
    int gt = blockIdx.x * blockDim.x + threadIdx.x;
    int wave = gt >> 6;
    int lane = threadIdx.x & 63;
    if (wave >= N) return;
    unsigned hi = h2u[(size_t)wave * 128 + lane];
    unsigned lo = h2u[(size_t)wave * 128 + 64 + lane];
    float2 v = unsplit2(hi, lo);
    float p = v.x * Wout[lane * 2] + v.y * Wout[lane * 2 + 1];
    #pragma unroll
    for (int off = 32; off; off >>= 1) p += __shfl_down(p, off);
    if (lane == 0) out[wave] = p + bout[0];
}

extern "C" void kernel_launch(void* const* d_in, const int* in_sizes, int n_in,
                              void* d_out, int out_size, void* d_ws, size_t ws_size,
                              hipStream_t stream) {
    const float* x    = (const float*)d_in[0];
    const void*  ei   = d_in[1];
    const float* W1   = (const float*)d_in[2];
    const float* b1   = (const float*)d_in[3];
    const float* W2   = (const float*)d_in[4];
    const float* b2   = (const float*)d_in[5];
    const float* W3   = (const float*)d_in[6];
    const float* b3   = (const float*)d_in[7];
    const float* W4   = (const float*)d_in[8];
    const float* b4   = (const float*)d_in[9];
    const float* Wout = (const float*)d_in[10];
    const float* bout = (const float*)d_in[11];
    float* out = (float*)d_out;

    const int E = in_sizes[1] / 2;
    const int N = N_NODES;
    const int nb = (N + 255) / 256;   // 196 scan blocks

    // ---- workspace layout (256B-aligned slots) ----
    char* wsb = (char*)d_ws;
    size_t off = 0;
    auto alloc = [&](size_t bytes) -> void* {
        void* p = wsb + off;
        off = (off + bytes + 255) & ~(size_t)255;
        return p;
    };
    int*    flag   = (int*)alloc(4);
    int*    deg    = (int*)alloc((size_t)N * 4);          // reused as cursor
    int*    rowptr = (int*)alloc((size_t)(N + 1) * 4);
    int*    bsum   = (int*)alloc(256 * 4);
    int*    bsx    = (int*)alloc(256 * 4);
    int*    col    = (int*)alloc((size_t)E * 4);
    ushort* w1h    = (ushort*)alloc(128 * 64 * 2);
    ushort* w1l    = (ushort*)alloc(128 * 64 * 2);
    ushort* w2h    = (ushort*)alloc(128 * 128 * 2);
    ushort* w2l    = (ushort*)alloc(128 * 128 * 2);
    ushort* w3h    = (ushort*)alloc(128 * 128 * 2);
    ushort* w3l    = (ushort*)alloc(128 * 128 * 2);
    ushort* w4h    = (ushort*)alloc(128 * 128 * 2);
    ushort* w4l    = (ushort*)alloc(128 * 128 * 2);
    // packed split tensors: P64 = N*128 ushorts, P128 = N*256 ushorts
    ushort* bufA   = (ushort*)alloc((size_t)N * 256 * 2);
    ushort* bufB   = (ushort*)alloc((size_t)N * 256 * 2);
    ushort* bufC   = (ushort*)alloc((size_t)N * 256 * 2);

    detect64_kernel<<<1, 256, 0, stream>>>((const int*)ei, flag);

    // ---- build CSR (once, reused by both layers) ----
    hipMemsetAsync(deg, 0, (size_t)N * sizeof(int), stream);
    hist_kernel<<<(E + 255) / 256, 256, 0, stream>>>(ei, flag, deg, E);
    scan1_kernel<<<nb, 256, 0, stream>>>(deg, rowptr, bsum, N);
    scan2_kernel<<<1, 256, 0, stream>>>(bsum, bsx, nb);
    scan3_kernel<<<nb, 256, 0, stream>>>(deg, rowptr, bsx, N);  // deg becomes cursor
    fill_kernel<<<(E + 255) / 256, 256, 0, stream>>>(ei, flag, deg, col, E);

    // ---- pre-split weights to bf16 hi/lo (transposed) ----
    wsplit_kernel<64> <<<(128 * 64 + 255) / 256, 256, 0, stream>>>(W1, w1h, w1l);
    wsplit_kernel<128><<<(128 * 128 + 255) / 256, 256, 0, stream>>>(W2, w2h, w2l);
    wsplit_kernel<128><<<(128 * 128 + 255) / 256, 256, 0, stream>>>(W3, w3h, w3l);
    wsplit_kernel<128><<<(128 * 128 + 255) / 256, 256, 0, stream>>>(W4, w4h, w4l);

    const int agg_blocks  = (N * 64 + 255) / 256;   // wave per node
    const int gemm_blocks = (N + 63) / 64;          // 782

    // ---- layer 1 ----
    gather_agg64_kernel<<<agg_blocks, 256, 0, stream>>>(x, rowptr, col, bufA, N);
    gemm_mfma_kernel<64><<<gemm_blocks, 256, 0, stream>>>(
        bufA, w1h, w1l, b1, bufB, N);                  // t1 = relu((x+agg)@W1+b1)
    gemm_mfma_kernel<128><<<gemm_blocks, 256, 0, stream>>>(
        bufB, w2h, w2l, b2, bufC, N);                  // h1 = relu(t1@W2+b2)

    // ---- layer 2 ----
    gather_agg128_kernel<<<agg_blocks, 256, 0, stream>>>(bufC, rowptr, col, bufA, N);
    gemm_mfma_kernel<128><<<gemm_blocks, 256, 0, stream>>>(
        bufA, w3h, w3l, b3, bufB, N);                  // t2
    gemm_mfma_kernel<128><<<gemm_blocks, 256, 0, stream>>>(
        bufB, w4h, w4l, b4, bufC, N);                  // h2

    // ---- output head ----
    out_dot_kernel<<<(N * 64 + 255) / 256, 256, 0, stream>>>(
        bufC, Wout, bout, out, N);
}

// Round 8
// 341.472 us; speedup vs baseline: 1.1157x; 1.1157x over previous
//
#include <hip/hip_runtime.h>

// GIN: 2x GINConv(eps=0, MLP 2-layer) + ReLU, then Linear(128->1).
// N=50000 nodes, E=800000 edges, IN=64, HID=128.
//
// Round 7 (resubmit — round 7 bench was a GPU-acquisition timeout, no data):
// full bf16 storage (threshold is bf16-grade: 5.3e-2), 1-pass MFMA,
// and fused MLP (both GEMMs in one kernel; t1 stays in LDS). Gathers move
// half the bytes. x pre-converted to a bf16 table for the layer-1 gather.

#define N_NODES 50000
#define IN_CH 64
#define HID 128

typedef short short8 __attribute__((ext_vector_type(8)));
typedef float f32x4 __attribute__((ext_vector_type(4)));

__device__ __forceinline__ unsigned bf16_rne(float f) {
    unsigned u = __float_as_uint(f);
    return (u + 0x7FFFu + ((u >> 16) & 1u)) >> 16;
}
__device__ __forceinline__ float bf16_to_f(ushort u) {
    return __uint_as_float(((unsigned)u) << 16);
}

// ---------------- edge dtype detection (int64 vs int32) ----------------
__global__ void detect64_kernel(const int* __restrict__ ei32, int* __restrict__ flag) {
    int t = threadIdx.x;  // 256 threads
    int v = ei32[2 * t + 1];
    unsigned long long b = __ballot(v != 0);
    __shared__ unsigned long long r[4];
    if ((t & 63) == 0) r[t >> 6] = b;
    __syncthreads();
    if (t == 0) flag[0] = ((r[0] | r[1] | r[2] | r[3]) == 0ULL) ? 1 : 0;
}

__device__ __forceinline__ int load_idx(const void* ei, int is64, int pos) {
    if (is64) return (int)((const long long*)ei)[pos];
    return ((const int*)ei)[pos];
}

// ---------------- CSR build ----------------
__global__ __launch_bounds__(256) void hist_kernel(
    const void* __restrict__ ei, const int* __restrict__ is64,
    int* __restrict__ deg, int E)
{
    int e = blockIdx.x * blockDim.x + threadIdx.x;
    if (e >= E) return;
    int d = load_idx(ei, *is64, E + e);
    atomicAdd(&deg[d], 1);
}

__device__ __forceinline__ int wave_incl_scan(int v, int lane) {
    #pragma unroll
    for (int off = 1; off < 64; off <<= 1) {
        int u = __shfl_up(v, off);
        if (lane >= off) v += u;
    }
    return v;
}

__global__ __launch_bounds__(256) void scan1_kernel(
    const int* __restrict__ deg, int* __restrict__ incl,
    int* __restrict__ bsum, int N)
{
    int i = blockIdx.x * 256 + threadIdx.x;
    int lane = threadIdx.x & 63;
    int w = threadIdx.x >> 6;
    int v = (i < N) ? deg[i] : 0;
    int s = wave_incl_scan(v, lane);
    __shared__ int wsum[4];
    if (lane == 63) wsum[w] = s;
    __syncthreads();
    int off = 0;
    #pragma unroll
    for (int k = 0; k < 4; k++) if (k < w) off += wsum[k];
    s += off;
    if (i < N) incl[i] = s;
    if (threadIdx.x == 255) bsum[blockIdx.x] = s;
}

__global__ __launch_bounds__(256) void scan2_kernel(
    const int* __restrict__ bsum, int* __restrict__ bsx, int nb)
{
    int t = threadIdx.x;
    int lane = t & 63;
    int w = t >> 6;
    int v = (t < nb) ? bsum[t] : 0;
    int s = wave_incl_scan(v, lane);
    __shared__ int wsum[4];
    if (lane == 63) wsum[w] = s;
    __syncthreads();
    int off = 0;
    #pragma unroll
    for (int k = 0; k < 4; k++) if (k < w) off += wsum[k];
    s += off;
    if (t < nb) bsx[t] = s - v;   // exclusive
}

__global__ __launch_bounds__(256) void scan3_kernel(
    int* __restrict__ deg_cursor, int* __restrict__ incl_rowptr,
    const int* __restrict__ bsx, int N)
{
    int i = blockIdx.x * 256 + threadIdx.x;
    if (i >= N) return;
    int incl = incl_rowptr[i] + bsx[blockIdx.x];
    int d = deg_cursor[i];
    int excl = incl - d;
    incl_rowptr[i] = excl;        // row_ptr[i]
    deg_cursor[i] = excl;         // cursor[i]
    if (i == N - 1) incl_rowptr[N] = incl;
}

__global__ __launch_bounds__(256) void fill_kernel(
    const void* __restrict__ ei, const int* __restrict__ is64,
    int* __restrict__ cursor, int* __restrict__ col, int E)
{
    int e = blockIdx.x * blockDim.x + threadIdx.x;
    if (e >= E) return;
    int i64 = *is64;
    int s = load_idx(ei, i64, e);
    int d = load_idx(ei, i64, E + e);
    int pos = atomicAdd(&cursor[d], 1);
    col[pos] = s;
}

// ---------------- x fp32 -> bf16 table ----------------
__global__ __launch_bounds__(256) void xconv_kernel(
    const float* __restrict__ x, ushort* __restrict__ xb, int total4)
{
    int i = blockIdx.x * 256 + threadIdx.x;
    if (i >= total4) return;
    float4 v = ((const float4*)x)[i];
    ushort4 o;
    o.x = (ushort)bf16_rne(v.x); o.y = (ushort)bf16_rne(v.y);
    o.z = (ushort)bf16_rne(v.z); o.w = (ushort)bf16_rne(v.w);
    ((ushort4*)xb)[i] = o;
}

// ---------------- W fp32 [K][128] -> bf16 [128][K] (transposed) ----------------
template<int K>
__global__ __launch_bounds__(256) void wconv_kernel(
    const float* __restrict__ W, ushort* __restrict__ Wt)
{
    int i = blockIdx.x * 256 + threadIdx.x;
    if (i >= 128 * K) return;
    int n = i / K, k = i % K;
    Wt[(size_t)n * K + k] = (ushort)bf16_rne(W[(size_t)k * 128 + n]);
}

// ---------------- gather64: out[n] = bf16( xb[n] + sum_j xb[j] ) ----------------
__global__ __launch_bounds__(256) void gather64_kernel(
    const ushort* __restrict__ xb, const int* __restrict__ rp,
    const int* __restrict__ col, ushort* __restrict__ outb, int N)
{
    int wid = (blockIdx.x * blockDim.x + threadIdx.x) >> 6;
    int lane = threadIdx.x & 63;
    if (wid >= N) return;
    int b = rp[wid], e2 = rp[wid + 1];
    float acc = bf16_to_f(xb[(size_t)wid * 64 + lane]);   // self term
    for (int base = b; base < e2; base += 64) {
        int cnt = e2 - base; if (cnt > 64) cnt = 64;
        int myc = (base + lane < e2) ? col[base + lane] : 0;
        for (int j = 0; j < cnt; j++) {
            int s = __shfl(myc, j);
            acc += bf16_to_f(xb[(size_t)s * 64 + lane]);
        }
    }
    outb[(size_t)wid * 64 + lane] = (ushort)bf16_rne(acc);
}

// ---------------- gather128: bf16 in/out, fp32 accum; lane = 1 uint = 2 ch ----------------
__global__ __launch_bounds__(256) void gather128_kernel(
    const ushort* __restrict__ in, const int* __restrict__ rp,
    const int* __restrict__ col, ushort* __restrict__ outb, int N)
{
    const unsigned* inu = (const unsigned*)in;
    unsigned* outu = (unsigned*)outb;
    int wid = (blockIdx.x * blockDim.x + threadIdx.x) >> 6;
    int lane = threadIdx.x & 63;
    if (wid >= N) return;
    int b = rp[wid], e2 = rp[wid + 1];
    unsigned u0 = inu[(size_t)wid * 64 + lane];
    float ax = __uint_as_float(u0 << 16);
    float ay = __uint_as_float(u0 & 0xFFFF0000u);
    for (int base = b; base < e2; base += 64) {
        int cnt = e2 - base; if (cnt > 64) cnt = 64;
        int myc = (base + lane < e2) ? col[base + lane] : 0;
        for (int j = 0; j < cnt; j++) {
            int s = __shfl(myc, j);
            unsigned u = inu[(size_t)s * 64 + lane];
            ax += __uint_as_float(u << 16);
            ay += __uint_as_float(u & 0xFFFF0000u);
        }
    }
    outu[(size_t)wid * 64 + lane] = bf16_rne(ax) | (bf16_rne(ay) << 16);
}

// ---------------- fused MLP: out = relu(relu(A@W1+b1)@W2+b2), all bf16 ----------------
// Block: 64 rows, 256 threads (4 waves x 16 rows). t1 lives in LDS.
// K1 = 64 or 128; second GEMM always 128x128.
template<int K1>
__global__ __launch_bounds__(256) void mlp_fused_kernel(
    const ushort* __restrict__ A, const ushort* __restrict__ W1t,
    const ushort* __restrict__ W2t, const float* __restrict__ b1,
    const float* __restrict__ b2, ushort* __restrict__ outb, int N)
{
    constexpr int SA = K1 + 8;                       // ushort stride (16B-mult)
    __shared__ __align__(16) ushort Asm[64 * SA];
    __shared__ __align__(16) ushort Wsm[128 * 136];  // W1 (stride SA) then W2 (stride 136)
    __shared__ __align__(16) ushort T1s[64 * 136];

    const int t  = threadIdx.x;
    const int n0 = blockIdx.x * 64;
    const int w  = t >> 6, l = t & 63;
    const int lr = l & 15, lg = l >> 4;

    // ---- stage A tile 64 x K1 (4 threads/row, K1/4 ushorts each) ----
    {
        int row = t >> 2, seg = t & 3;
        int n = n0 + row; int nc = n < N ? n : N - 1;
        const uint4* src = (const uint4*)(A + (size_t)nc * K1 + seg * (K1 / 4));
        uint4* dst = (uint4*)&Asm[row * SA + seg * (K1 / 4)];
        #pragma unroll
        for (int q = 0; q < K1 / 32; q++) dst[q] = src[q];
    }
    // ---- stage W1t 128 x K1 (2 threads/row, K1/2 ushorts each) ----
    {
        int n = t >> 1, half = t & 1;
        const uint4* src = (const uint4*)(W1t + (size_t)n * K1 + half * (K1 / 2));
        uint4* dst = (uint4*)&Wsm[n * SA + half * (K1 / 2)];
        #pragma unroll
        for (int q = 0; q < K1 / 16; q++) dst[q] = src[q];
    }
    __syncthreads();

    // ---- pass 1: t1 = relu(A @ W1 + b1) ----
    f32x4 acc[8];
    #pragma unroll
    for (int c = 0; c < 8; c++) acc[c] = (f32x4){0.f, 0.f, 0.f, 0.f};
    #pragma unroll
    for (int ks = 0; ks < K1 / 32; ks++) {
        short8 a = *(const short8*)&Asm[(w * 16 + lr) * SA + ks * 32 + lg * 8];
        #pragma unroll
        for (int c = 0; c < 8; c++) {
            short8 bb = *(const short8*)&Wsm[(c * 16 + lr) * SA + ks * 32 + lg * 8];
            acc[c] = __builtin_amdgcn_mfma_f32_16x16x32_bf16(a, bb, acc[c], 0, 0, 0);
        }
    }
    #pragma unroll
    for (int c = 0; c < 8; c++) {
        float bc = b1[c * 16 + lr];
        #pragma unroll
        for (int j = 0; j < 4; j++) {
            float v = fmaxf(acc[c][j] + bc, 0.f);
            T1s[(w * 16 + lg * 4 + j) * 136 + c * 16 + lr] = (ushort)bf16_rne(v);
        }
    }
    __syncthreads();   // T1 complete; Wsm pass-1 reads done

    // ---- stage W2t 128 x 128 over Wsm (stride 136) ----
    {
        int n = t >> 1, half = t & 1;
        const uint4* src = (const uint4*)(W2t + (size_t)n * 128 + half * 64);
        uint4* dst = (uint4*)&Wsm[n * 136 + half * 64];
        #pragma unroll
        for (int q = 0; q < 8; q++) dst[q] = src[q];
    }
    __syncthreads();

    // ---- pass 2: h = relu(t1 @ W2 + b2) ----
    #pragma unroll
    for (int c = 0; c < 8; c++) acc[c] = (f32x4){0.f, 0.f, 0.f, 0.f};
    #pragma unroll
    for (int ks = 0; ks < 4; ks++) {
        short8 a = *(const short8*)&T1s[(w * 16 + lr) * 136 + ks * 32 + lg * 8];
        #pragma unroll
        for (int c = 0; c < 8; c++) {
            short8 bb = *(const short8*)&Wsm[(c * 16 + lr) * 136 + ks * 32 + lg * 8];
            acc[c] = __builtin_amdgcn_mfma_f32_16x16x32_bf16(a, bb, acc[c], 0, 0, 0);
        }
    }
    #pragma unroll
    for (int c = 0; c < 8; c++) {
        float bc = b2[c * 16 + lr];
        #pragma unroll
        for (int j = 0; j < 4; j++) {
            int row = n0 + w * 16 + lg * 4 + j;
            if (row < N) {
                float v = fmaxf(acc[c][j] + bc, 0.f);
                outb[(size_t)row * 128 + c * 16 + lr] = (ushort)bf16_rne(v);
            }
        }
    }
}

// ---------------- output head: out[n] = dot(h2[n], Wout) + bout ----------------
__global__ __launch_bounds__(256) void out_dot_kernel(
    const ushort* __restrict__ h2, const float* __restrict__ Wout,
    const float* __restrict__ bout, float* __restrict__ out, int N)
{
    const unsigned* hu = (const unsigned*)h2;
    int wave = (blockIdx.x * blockDim.x + threadIdx.x) >> 6;
    int lane = threadIdx.x & 63;
    if (wave >= N) return;
    unsigned u = hu[(size_t)wave * 64 + lane];
    float a = __uint_as_float(u << 16);
    float b = __uint_as_float(u & 0xFFFF0000u);
    float p = a * Wout[lane * 2] + b * Wout[lane * 2 + 1];
    #pragma unroll
    for (int off = 32; off; off >>= 1) p += __shfl_down(p, off);
    if (lane == 0) out[wave] = p + bout[0];
}

extern "C" void kernel_launch(void* const* d_in, const int* in_sizes, int n_in,
                              void* d_out, int out_size, void* d_ws, size_t ws_size,
                              hipStream_t stream) {
    const float* x    = (const float*)d_in[0];
    const void*  ei   = d_in[1];
    const float* W1   = (const float*)d_in[2];
    const float* b1   = (const float*)d_in[3];
    const float* W2   = (const float*)d_in[4];
    const float* b2   = (const float*)d_in[5];
    const float* W3   = (const float*)d_in[6];
    const float* b3   = (const float*)d_in[7];
    const float* W4   = (const float*)d_in[8];
    const float* b4   = (const float*)d_in[9];
    const float* Wout = (const float*)d_in[10];
    const float* bout = (const float*)d_in[11];
    float* out = (float*)d_out;

    const int E = in_sizes[1] / 2;
    const int N = N_NODES;
    const int nb = (N + 255) / 256;

    // ---- workspace layout (256B-aligned slots) ----
    char* wsb = (char*)d_ws;
    size_t off = 0;
    auto alloc = [&](size_t bytes) -> void* {
        void* p = wsb + off;
        off = (off + bytes + 255) & ~(size_t)255;
        return p;
    };
    int*    flag   = (int*)alloc(4);
    int*    deg    = (int*)alloc((size_t)N * 4);
    int*    rowptr = (int*)alloc((size_t)(N + 1) * 4);
    int*    bsum   = (int*)alloc(256 * 4);
    int*    bsx    = (int*)alloc(256 * 4);
    int*    col    = (int*)alloc((size_t)E * 4);
    ushort* xb     = (ushort*)alloc((size_t)N * 64 * 2);
    ushort* w1t    = (ushort*)alloc(128 * 64 * 2);
    ushort* w2t    = (ushort*)alloc(128 * 128 * 2);
    ushort* w3t    = (ushort*)alloc(128 * 128 * 2);
    ushort* w4t    = (ushort*)alloc(128 * 128 * 2);
    ushort* agg1   = (ushort*)alloc((size_t)N * 64 * 2);    // layer-1 MLP input
    ushort* h1     = (ushort*)alloc((size_t)N * 128 * 2);
    ushort* agg2   = (ushort*)alloc((size_t)N * 128 * 2);
    ushort* h2     = (ushort*)alloc((size_t)N * 128 * 2);

    detect64_kernel<<<1, 256, 0, stream>>>((const int*)ei, flag);

    // ---- build CSR ----
    hipMemsetAsync(deg, 0, (size_t)N * sizeof(int), stream);
    hist_kernel<<<(E + 255) / 256, 256, 0, stream>>>(ei, flag, deg, E);
    scan1_kernel<<<nb, 256, 0, stream>>>(deg, rowptr, bsum, N);
    scan2_kernel<<<1, 256, 0, stream>>>(bsum, bsx, nb);
    scan3_kernel<<<nb, 256, 0, stream>>>(deg, rowptr, bsx, N);
    fill_kernel<<<(E + 255) / 256, 256, 0, stream>>>(ei, flag, deg, col, E);

    // ---- convert inputs to bf16 ----
    xconv_kernel<<<(N * 64 / 4 + 255) / 256, 256, 0, stream>>>(x, xb, N * 64 / 4);
    wconv_kernel<64> <<<(128 * 64 + 255) / 256, 256, 0, stream>>>(W1, w1t);
    wconv_kernel<128><<<(128 * 128 + 255) / 256, 256, 0, stream>>>(W2, w2t);
    wconv_kernel<128><<<(128 * 128 + 255) / 256, 256, 0, stream>>>(W3, w3t);
    wconv_kernel<128><<<(128 * 128 + 255) / 256, 256, 0, stream>>>(W4, w4t);

    const int agg_blocks = (N * 64 + 255) / 256;   // wave per node
    const int mlp_blocks = (N + 63) / 64;          // 782

    // ---- layer 1 ----
    gather64_kernel<<<agg_blocks, 256, 0, stream>>>(xb, rowptr, col, agg1, N);
    mlp_fused_kernel<64><<<mlp_blocks, 256, 0, stream>>>(
        agg1, w1t, w2t, b1, b2, h1, N);

    // ---- layer 2 ----
    gather128_kernel<<<agg_blocks, 256, 0, stream>>>(h1, rowptr, col, agg2, N);
    mlp_fused_kernel<128><<<mlp_blocks, 256, 0, stream>>>(
        agg2, w3t, w4t, b3, b4, h2, N);

    // ---- output head ----
    out_dot_kernel<<<(N * 64 + 255) / 256, 256, 0, stream>>>(
        h2, Wout, bout, out, N);
}

// Round 10
// 274.513 us; speedup vs baseline: 1.3879x; 1.2439x over previous
//
#include <hip/hip_runtime.h>

// GIN: 2x GINConv(eps=0, MLP 2-layer) + ReLU, then Linear(128->1).
// N=50000 nodes, E=800000 edges, IN=64, HID=128.
//
// Round 9 (resubmit — round 9 bench was an infra container failure, no data):
// (a) XCD-affine dst-partitioned CSR build (hist8/fill8) to kill
// the 53MB col/deg line-bounce write-backs (fill was 56us @ ~1TB/s);
// (b) gather64 processes 2 neighbors/iter with full-width uint loads;
// (c) gather128 2x unrolled for MLP; (d) output head fused into mlp128
// (h2 never hits memory); (e) wconv merged into one launch.

#define N_NODES 50000
#define IN_CH 64
#define HID 128
#define REGION 6250   // N/8 dst-nodes per XCD-affine region

typedef short short8 __attribute__((ext_vector_type(8)));
typedef float f32x4 __attribute__((ext_vector_type(4)));

__device__ __forceinline__ unsigned bf16_rne(float f) {
    unsigned u = __float_as_uint(f);
    return (u + 0x7FFFu + ((u >> 16) & 1u)) >> 16;
}
__device__ __forceinline__ float bf16_to_f(ushort u) {
    return __uint_as_float(((unsigned)u) << 16);
}
__device__ __forceinline__ float lo_f(unsigned u) { return __uint_as_float(u << 16); }
__device__ __forceinline__ float hi_f(unsigned u) { return __uint_as_float(u & 0xFFFF0000u); }

// ---------------- edge dtype detection (int64 vs int32) ----------------
__global__ void detect64_kernel(const int* __restrict__ ei32, int* __restrict__ flag) {
    int t = threadIdx.x;  // 256 threads
    int v = ei32[2 * t + 1];
    unsigned long long b = __ballot(v != 0);
    __shared__ unsigned long long r[4];
    if ((t & 63) == 0) r[t >> 6] = b;
    __syncthreads();
    if (t == 0) flag[0] = ((r[0] | r[1] | r[2] | r[3]) == 0ULL) ? 1 : 0;
}

__device__ __forceinline__ int load_idx(const void* ei, int is64, int pos) {
    if (is64) return (int)((const long long*)ei)[pos];
    return ((const int*)ei)[pos];
}

// ---------------- CSR build, XCD-affine (bid%8 == dst region) ----------------
__global__ __launch_bounds__(256) void hist8_kernel(
    const void* __restrict__ ei, const int* __restrict__ is64,
    int* __restrict__ deg, int E, int nsub)
{
    int g   = blockIdx.x & 7;
    int sub = blockIdx.x >> 3;
    int i64 = *is64;
    int lo = g * REGION, hi = lo + REGION;
    for (int e = sub * 256 + threadIdx.x; e < E; e += nsub * 256) {
        int d = load_idx(ei, i64, E + e);
        if (d >= lo && d < hi) atomicAdd(&deg[d], 1);
    }
}

__global__ __launch_bounds__(256) void fill8_kernel(
    const void* __restrict__ ei, const int* __restrict__ is64,
    int* __restrict__ cursor, int* __restrict__ col, int E, int nsub)
{
    int g   = blockIdx.x & 7;
    int sub = blockIdx.x >> 3;
    int i64 = *is64;
    int lo = g * REGION, hi = lo + REGION;
    for (int e = sub * 256 + threadIdx.x; e < E; e += nsub * 256) {
        int d = load_idx(ei, i64, E + e);
        if (d >= lo && d < hi) {
            int s = load_idx(ei, i64, e);
            int pos = atomicAdd(&cursor[d], 1);
            col[pos] = s;
        }
    }
}

__device__ __forceinline__ int wave_incl_scan(int v, int lane) {
    #pragma unroll
    for (int off = 1; off < 64; off <<= 1) {
        int u = __shfl_up(v, off);
        if (lane >= off) v += u;
    }
    return v;
}

__global__ __launch_bounds__(256) void scan1_kernel(
    const int* __restrict__ deg, int* __restrict__ incl,
    int* __restrict__ bsum, int N)
{
    int i = blockIdx.x * 256 + threadIdx.x;
    int lane = threadIdx.x & 63;
    int w = threadIdx.x >> 6;
    int v = (i < N) ? deg[i] : 0;
    int s = wave_incl_scan(v, lane);
    __shared__ int wsum[4];
    if (lane == 63) wsum[w] = s;
    __syncthreads();
    int off = 0;
    #pragma unroll
    for (int k = 0; k < 4; k++) if (k < w) off += wsum[k];
    s += off;
    if (i < N) incl[i] = s;
    if (threadIdx.x == 255) bsum[blockIdx.x] = s;
}

__global__ __launch_bounds__(256) void scan2_kernel(
    const int* __restrict__ bsum, int* __restrict__ bsx, int nb)
{
    int t = threadIdx.x;
    int lane = t & 63;
    int w = t >> 6;
    int v = (t < nb) ? bsum[t] : 0;
    int s = wave_incl_scan(v, lane);
    __shared__ int wsum[4];
    if (lane == 63) wsum[w] = s;
    __syncthreads();
    int off = 0;
    #pragma unroll
    for (int k = 0; k < 4; k++) if (k < w) off += wsum[k];
    s += off;
    if (t < nb) bsx[t] = s - v;   // exclusive
}

__global__ __launch_bounds__(256) void scan3_kernel(
    int* __restrict__ deg_cursor, int* __restrict__ incl_rowptr,
    const int* __restrict__ bsx, int N)
{
    int i = blockIdx.x * 256 + threadIdx.x;
    if (i >= N) return;
    int incl = incl_rowptr[i] + bsx[blockIdx.x];
    int d = deg_cursor[i];
    int excl = incl - d;
    incl_rowptr[i] = excl;        // row_ptr[i]
    deg_cursor[i] = excl;         // cursor[i]
    if (i == N - 1) incl_rowptr[N] = incl;
}

// ---------------- x fp32 -> bf16 table ----------------
__global__ __launch_bounds__(256) void xconv_kernel(
    const float* __restrict__ x, ushort* __restrict__ xb, int total4)
{
    int i = blockIdx.x * 256 + threadIdx.x;
    if (i >= total4) return;
    float4 v = ((const float4*)x)[i];
    ushort4 o;
    o.x = (ushort)bf16_rne(v.x); o.y = (ushort)bf16_rne(v.y);
    o.z = (ushort)bf16_rne(v.z); o.w = (ushort)bf16_rne(v.w);
    ((ushort4*)xb)[i] = o;
}

// ---------------- all W fp32 [K][128] -> bf16 [128][K] (transposed), one launch ----------------
__global__ __launch_bounds__(256) void wconv_all_kernel(
    const float* __restrict__ W1, const float* __restrict__ W2,
    const float* __restrict__ W3, const float* __restrict__ W4,
    ushort* __restrict__ w1t, ushort* __restrict__ w2t,
    ushort* __restrict__ w3t, ushort* __restrict__ w4t)
{
    int i = blockIdx.x * 256 + threadIdx.x;
    if (i < 8192) {                       // W1: 128 x 64
        int n = i >> 6, k = i & 63;
        w1t[i] = (ushort)bf16_rne(W1[(size_t)k * 128 + n]);
    } else if (i < 8192 + 16384) {
        int j = i - 8192; int n = j >> 7, k = j & 127;
        w2t[j] = (ushort)bf16_rne(W2[(size_t)k * 128 + n]);
    } else if (i < 8192 + 32768) {
        int j = i - 8192 - 16384; int n = j >> 7, k = j & 127;
        w3t[j] = (ushort)bf16_rne(W3[(size_t)k * 128 + n]);
    } else if (i < 8192 + 49152) {
        int j = i - 8192 - 32768; int n = j >> 7, k = j & 127;
        w4t[j] = (ushort)bf16_rne(W4[(size_t)k * 128 + n]);
    }
}

// ---------------- gather64: 2 neighbors/iter; row = 32 uints (64ch bf16) ----------------
__global__ __launch_bounds__(256) void gather64_kernel(
    const ushort* __restrict__ xb, const int* __restrict__ rp,
    const int* __restrict__ col, ushort* __restrict__ outb, int N)
{
    const unsigned* xu = (const unsigned*)xb;
    unsigned* outu = (unsigned*)outb;
    int wid = (blockIdx.x * blockDim.x + threadIdx.x) >> 6;
    int lane = threadIdx.x & 63;
    int half = lane >> 5, cl = lane & 31;
    if (wid >= N) return;
    int b = rp[wid], e2 = rp[wid + 1];
    unsigned us = xu[(size_t)wid * 32 + cl];
    float ax = (half == 0) ? lo_f(us) : 0.f;
    float ay = (half == 0) ? hi_f(us) : 0.f;
    for (int base = b; base < e2; base += 64) {
        int cnt = e2 - base; if (cnt > 64) cnt = 64;
        int myc = (base + lane < e2) ? col[base + lane] : 0;
        for (int j = 0; j < cnt; j += 2) {
            int jj = j + half;                 // half 0: even, half 1: odd
            int s = __shfl(myc, jj);           // jj==cnt (odd tail) -> myc=0, masked below
            unsigned u = xu[(size_t)s * 32 + cl];
            if (jj < cnt) { ax += lo_f(u); ay += hi_f(u); }
        }
    }
    ax += __shfl_xor(ax, 32);
    ay += __shfl_xor(ay, 32);
    if (half == 0) outu[(size_t)wid * 32 + cl] = bf16_rne(ax) | (bf16_rne(ay) << 16);
}

// ---------------- gather128: bf16 in/out, fp32 accum, 2x unrolled ----------------
__global__ __launch_bounds__(256) void gather128_kernel(
    const ushort* __restrict__ in, const int* __restrict__ rp,
    const int* __restrict__ col, ushort* __restrict__ outb, int N)
{
    const unsigned* inu = (const unsigned*)in;
    unsigned* outu = (unsigned*)outb;
    int wid = (blockIdx.x * blockDim.x + threadIdx.x) >> 6;
    int lane = threadIdx.x & 63;
    if (wid >= N) return;
    int b = rp[wid], e2 = rp[wid + 1];
    unsigned u0 = inu[(size_t)wid * 64 + lane];
    float ax = lo_f(u0), ay = hi_f(u0);
    float bx = 0.f, by = 0.f;
    for (int base = b; base < e2; base += 64) {
        int cnt = e2 - base; if (cnt > 64) cnt = 64;
        int myc = (base + lane < e2) ? col[base + lane] : 0;
        int j = 0;
        for (; j + 1 < cnt; j += 2) {
            int s0 = __shfl(myc, j), s1 = __shfl(myc, j + 1);
            unsigned ua = inu[(size_t)s0 * 64 + lane];
            unsigned ub = inu[(size_t)s1 * 64 + lane];
            ax += lo_f(ua); ay += hi_f(ua);
            bx += lo_f(ub); by += hi_f(ub);
        }
        if (j < cnt) {
            int s = __shfl(myc, j);
            unsigned u = inu[(size_t)s * 64 + lane];
            ax += lo_f(u); ay += hi_f(u);
        }
    }
    ax += bx; ay += by;
    outu[(size_t)wid * 64 + lane] = bf16_rne(ax) | (bf16_rne(ay) << 16);
}

// ---------------- fused MLP (+ optional output head) ----------------
// out = relu(relu(A@W1+b1)@W2+b2); HEAD: fout[n] = dot(out_row, Wout)+bout,
// and the bf16 row is NOT written. Block: 64 rows, 256 threads.
template<int K1, bool HEAD>
__global__ __launch_bounds__(256) void mlp_fused_kernel(
    const ushort* __restrict__ A, const ushort* __restrict__ W1t,
    const ushort* __restrict__ W2t, const float* __restrict__ b1,
    const float* __restrict__ b2, ushort* __restrict__ outb,
    const float* __restrict__ Wout, const float* __restrict__ bout,
    float* __restrict__ fout, int N)
{
    constexpr int SA = K1 + 8;                       // ushort stride (16B-mult)
    __shared__ __align__(16) ushort Asm[64 * SA];
    __shared__ __align__(16) ushort Wsm[128 * 136];  // W1 (stride SA) then W2 (stride 136)
    __shared__ __align__(16) ushort T1s[64 * 136];

    const int t  = threadIdx.x;
    const int n0 = blockIdx.x * 64;
    const int w  = t >> 6, l = t & 63;
    const int lr = l & 15, lg = l >> 4;

    // ---- stage A tile 64 x K1 (4 threads/row) ----
    {
        int row = t >> 2, seg = t & 3;
        int n = n0 + row; int nc = n < N ? n : N - 1;
        const uint4* src = (const uint4*)(A + (size_t)nc * K1 + seg * (K1 / 4));
        uint4* dst = (uint4*)&Asm[row * SA + seg * (K1 / 4)];
        #pragma unroll
        for (int q = 0; q < K1 / 32; q++) dst[q] = src[q];
    }
    // ---- stage W1t 128 x K1 (2 threads/row) ----
    {
        int n = t >> 1, half = t & 1;
        const uint4* src = (const uint4*)(W1t + (size_t)n * K1 + half * (K1 / 2));
        uint4* dst = (uint4*)&Wsm[n * SA + half * (K1 / 2)];
        #pragma unroll
        for (int q = 0; q < K1 / 16; q++) dst[q] = src[q];
    }
    __syncthreads();

    // ---- pass 1: t1 = relu(A @ W1 + b1) ----
    f32x4 acc[8];
    #pragma unroll
    for (int c = 0; c < 8; c++) acc[c] = (f32x4){0.f, 0.f, 0.f, 0.f};
    #pragma unroll
    for (int ks = 0; ks < K1 / 32; ks++) {
        short8 a = *(const short8*)&Asm[(w * 16 + lr) * SA + ks * 32 + lg * 8];
        #pragma unroll
        for (int c = 0; c < 8; c++) {
            short8 bb = *(const short8*)&Wsm[(c * 16 + lr) * SA + ks * 32 + lg * 8];
            acc[c] = __builtin_amdgcn_mfma_f32_16x16x32_bf16(a, bb, acc[c], 0, 0, 0);
        }
    }
    #pragma unroll
    for (int c = 0; c < 8; c++) {
        float bc = b1[c * 16 + lr];
        #pragma unroll
        for (int j = 0; j < 4; j++) {
            float v = fmaxf(acc[c][j] + bc, 0.f);
            T1s[(w * 16 + lg * 4 + j) * 136 + c * 16 + lr] = (ushort)bf16_rne(v);
        }
    }
    __syncthreads();   // T1 complete; Wsm pass-1 reads done

    // ---- stage W2t 128 x 128 over Wsm (stride 136) ----
    {
        int n = t >> 1, half = t & 1;
        const uint4* src = (const uint4*)(W2t + (size_t)n * 128 + half * 64);
        uint4* dst = (uint4*)&Wsm[n * 136 + half * 64];
        #pragma unroll
        for (int q = 0; q < 8; q++) dst[q] = src[q];
    }
    __syncthreads();

    // ---- pass 2: h = relu(t1 @ W2 + b2) ----
    #pragma unroll
    for (int c = 0; c < 8; c++) acc[c] = (f32x4){0.f, 0.f, 0.f, 0.f};
    #pragma unroll
    for (int ks = 0; ks < 4; ks++) {
        short8 a = *(const short8*)&T1s[(w * 16 + lr) * 136 + ks * 32 + lg * 8];
        #pragma unroll
        for (int c = 0; c < 8; c++) {
            short8 bb = *(const short8*)&Wsm[(c * 16 + lr) * 136 + ks * 32 + lg * 8];
            acc[c] = __builtin_amdgcn_mfma_f32_16x16x32_bf16(a, bb, acc[c], 0, 0, 0);
        }
    }
    if (HEAD) {
        // fout[n] = sum_ch relu(h)[ch] * Wout[ch] + bout; reduce over lr lanes
        float wv[8];
        #pragma unroll
        for (int c = 0; c < 8; c++) wv[c] = Wout[c * 16 + lr];
        float p[4] = {0.f, 0.f, 0.f, 0.f};
        #pragma unroll
        for (int c = 0; c < 8; c++) {
            float bc = b2[c * 16 + lr];
            #pragma unroll
            for (int j = 0; j < 4; j++) {
                float v = fmaxf(acc[c][j] + bc, 0.f);
                p[j] += v * wv[c];
            }
        }
        #pragma unroll
        for (int j = 0; j < 4; j++)
            #pragma unroll
            for (int off = 1; off < 16; off <<= 1) p[j] += __shfl_xor(p[j], off);
        if (lr == 0) {
            int row0 = n0 + w * 16 + lg * 4;
            float bo = bout[0];
            #pragma unroll
            for (int j = 0; j < 4; j++)
                if (row0 + j < N) fout[row0 + j] = p[j] + bo;
        }
    } else {
        #pragma unroll
        for (int c = 0; c < 8; c++) {
            float bc = b2[c * 16 + lr];
            #pragma unroll
            for (int j = 0; j < 4; j++) {
                int row = n0 + w * 16 + lg * 4 + j;
                if (row < N) {
                    float v = fmaxf(acc[c][j] + bc, 0.f);
                    outb[(size_t)row * 128 + c * 16 + lr] = (ushort)bf16_rne(v);
                }
            }
        }
    }
}

extern "C" void kernel_launch(void* const* d_in, const int* in_sizes, int n_in,
                              void* d_out, int out_size, void* d_ws, size_t ws_size,
                              hipStream_t stream) {
    const float* x    = (const float*)d_in[0];
    const void*  ei   = d_in[1];
    const float* W1   = (const float*)d_in[2];
    const float* b1   = (const float*)d_in[3];
    const float* W2   = (const float*)d_in[4];
    const float* b2   = (const float*)d_in[5];
    const float* W3   = (const float*)d_in[6];
    const float* b3   = (const float*)d_in[7];
    const float* W4   = (const float*)d_in[8];
    const float* b4   = (const float*)d_in[9];
    const float* Wout = (const float*)d_in[10];
    const float* bout = (const float*)d_in[11];
    float* out = (float*)d_out;

    const int E = in_sizes[1] / 2;
    const int N = N_NODES;
    const int nb = (N + 255) / 256;

    // ---- workspace layout (256B-aligned slots) ----
    char* wsb = (char*)d_ws;
    size_t off = 0;
    auto alloc = [&](size_t bytes) -> void* {
        void* p = wsb + off;
        off = (off + bytes + 255) & ~(size_t)255;
        return p;
    };
    int*    flag   = (int*)alloc(4);
    int*    deg    = (int*)alloc((size_t)N * 4);
    int*    rowptr = (int*)alloc((size_t)(N + 1) * 4);
    int*    bsum   = (int*)alloc(256 * 4);
    int*    bsx    = (int*)alloc(256 * 4);
    int*    col    = (int*)alloc((size_t)E * 4);
    ushort* xb     = (ushort*)alloc((size_t)N * 64 * 2);
    ushort* w1t    = (ushort*)alloc(128 * 64 * 2);
    ushort* w2t    = (ushort*)alloc(128 * 128 * 2);
    ushort* w3t    = (ushort*)alloc(128 * 128 * 2);
    ushort* w4t    = (ushort*)alloc(128 * 128 * 2);
    ushort* agg1   = (ushort*)alloc((size_t)N * 64 * 2);
    ushort* h1     = (ushort*)alloc((size_t)N * 128 * 2);
    ushort* agg2   = (ushort*)alloc((size_t)N * 128 * 2);

    detect64_kernel<<<1, 256, 0, stream>>>((const int*)ei, flag);

    // ---- build CSR (XCD-affine hist/fill) ----
    hipMemsetAsync(deg, 0, (size_t)N * sizeof(int), stream);
    hist8_kernel<<<2048, 256, 0, stream>>>(ei, flag, deg, E, 256);
    scan1_kernel<<<nb, 256, 0, stream>>>(deg, rowptr, bsum, N);
    scan2_kernel<<<1, 256, 0, stream>>>(bsum, bsx, nb);
    scan3_kernel<<<nb, 256, 0, stream>>>(deg, rowptr, bsx, N);   // deg becomes cursor
    fill8_kernel<<<2048, 256, 0, stream>>>(ei, flag, deg, col, E, 256);

    // ---- convert inputs to bf16 ----
    xconv_kernel<<<(N * 64 / 4 + 255) / 256, 256, 0, stream>>>(x, xb, N * 64 / 4);
    wconv_all_kernel<<<(8192 + 49152 + 255) / 256, 256, 0, stream>>>(
        W1, W2, W3, W4, w1t, w2t, w3t, w4t);

    const int agg_blocks = (N * 64 + 255) / 256;   // wave per node
    const int mlp_blocks = (N + 63) / 64;          // 782

    // ---- layer 1 ----
    gather64_kernel<<<agg_blocks, 256, 0, stream>>>(xb, rowptr, col, agg1, N);
    mlp_fused_kernel<64, false><<<mlp_blocks, 256, 0, stream>>>(
        agg1, w1t, w2t, b1, b2, h1, nullptr, nullptr, nullptr, N);

    // ---- layer 2 (+ fused output head) ----
    gather128_kernel<<<agg_blocks, 256, 0, stream>>>(h1, rowptr, col, agg2, N);
    mlp_fused_kernel<128, true><<<mlp_blocks, 256, 0, stream>>>(
        agg2, w3t, w4t, b3, b4, nullptr, Wout, bout, out, N);
}